// Round 10
// baseline (407.272 us; speedup 1.0000x reference)
//
#include <hip/hip_runtime.h>
#include <math.h>

#define N_NODES 50000
#define N_EDGES 1600000
#define IN_F 256
#define HID 128
#define NCLS 40
#define HS2 40        // f16 row stride for h2 (80 B exact; table = 4.0 MB)
#define NP 50048      // padded node count (ws layout)
#define NBINS 196     // ceil(50000/256) coarse bins of 256 nodes
#define MS_BLOCKS 200
#define MS_CHUNK 8000 // MS_BLOCKS * MS_CHUNK == N_EDGES
#define BC_BLOCKS 400
#define BC_CHUNK 4000 // BC_BLOCKS * BC_CHUNK == N_EDGES
#define BIN_CAP 12288 // max edges per 256-node bin (mean 8192, sigma ~90)

typedef __attribute__((ext_vector_type(8))) short short8;     // 8 bf16 (4 VGPRs)
typedef __attribute__((ext_vector_type(4))) float v4f;        // MFMA acc
typedef __attribute__((ext_vector_type(2))) _Float16 h2v;     // packed f16 pair

__device__ __forceinline__ unsigned short f2bf(float f) {
    union { float f; unsigned int i; } v;
    v.f = f;
    unsigned int r = v.i + 0x7FFF + ((v.i >> 16) & 1);  // RNE
    return (unsigned short)(r >> 16);
}
__device__ __forceinline__ h2v u2h(unsigned int u) {
    union { unsigned int i; h2v h; } v; v.i = u; return v.h;
}
__device__ __forceinline__ unsigned int h2u(h2v h) {
    union { h2v h; unsigned int i; } v; v.h = h; return v.i;
}

// ---------------- W1 preconvert + hist zero (fused) ---------------------------

__global__ __launch_bounds__(256) void k_w1cvt(const float* __restrict__ W1,
                                               short* __restrict__ w1f,
                                               int* __restrict__ hist_g) {
    if (blockIdx.x == 16) {
        for (int i = threadIdx.x; i < 2 * NBINS; i += 256) hist_g[i] = 0;
        return;
    }
    int g = blockIdx.x * 256 + threadIdx.x;   // slot id: 8 kt * 8 nt * 64 lanes = 4096
    int lane = g & 63, nt = (g >> 6) & 7, kt = g >> 9;
    int q = lane >> 4, n = lane & 15;
    short8 v;
#pragma unroll
    for (int j = 0; j < 8; j++) {
        int k = kt * 32 + q * 8 + j;
        v[j] = (short)f2bf(W1[(size_t)k * HID + nt * 16 + n]);
    }
    *(short8*)&w1f[(size_t)g * 8] = v;
}

// ---------------- binned CSR construction (no random atomics/stores) ----------

__global__ __launch_bounds__(256) void k_bincount(const int* __restrict__ src,
                                                  const int* __restrict__ dst,
                                                  int* __restrict__ hist_g) {
    __shared__ int h[2 * NBINS];
    int t = threadIdx.x;
    for (int i = t; i < 2 * NBINS; i += 256) h[i] = 0;
    __syncthreads();
    int e0 = blockIdx.x * BC_CHUNK;
    for (int i = t; i < BC_CHUNK; i += 256) {
        atomicAdd(&h[dst[e0 + i] >> 8], 1);
        atomicAdd(&h[NBINS + (src[e0 + i] >> 8)], 1);
    }
    __syncthreads();
    for (int i = t; i < 2 * NBINS; i += 256)
        if (h[i]) atomicAdd(&hist_g[i], h[i]);
}

__global__ __launch_bounds__(256) void k_binscan(const int* __restrict__ hist_g,
                                                 int* __restrict__ bo_d, int* __restrict__ bo_s,
                                                 int* __restrict__ cur_d, int* __restrict__ cur_s) {
    __shared__ int sm[256];
    int t = threadIdx.x;
    for (int side = 0; side < 2; side++) {
        int v = (t < NBINS) ? hist_g[side * NBINS + t] : 0;
        sm[t] = v;
        __syncthreads();
        for (int off = 1; off < 256; off <<= 1) {
            int a = (t >= off) ? sm[t - off] : 0;
            __syncthreads();
            sm[t] += a;
            __syncthreads();
        }
        int ex = sm[t] - v;
        int* bo = side ? bo_s : bo_d;
        int* cu = side ? cur_s : cur_d;
        if (t < NBINS) { bo[t] = ex; cu[t] = ex; }
        if (t == 0) bo[NBINS] = N_EDGES;
        __syncthreads();
    }
}

// multisplit: blocks [0,200) key=dst (payload src, packed int), blocks [200,400) key=src (1B payload)
__global__ __launch_bounds__(256) void k_msscatter(const int* __restrict__ src,
                                                   const int* __restrict__ dst,
                                                   int* __restrict__ cur_d, int* __restrict__ cur_s,
                                                   int* __restrict__ binned_d,
                                                   unsigned char* __restrict__ binned_s) {
    __shared__ int hist[NBINS];
    __shared__ int delta[NBINS];
    __shared__ int lcur[NBINS];
    __shared__ int sm[256];
    __shared__ int stage[MS_CHUNK];
    __shared__ unsigned char binof[MS_CHUNK];
    int t = threadIdx.x;
    int side = blockIdx.x / MS_BLOCKS;
    int e0 = (blockIdx.x % MS_BLOCKS) * MS_CHUNK;
    const int* key = side ? src : dst;
    for (int i = t; i < NBINS; i += 256) hist[i] = 0;
    __syncthreads();
    for (int i = t; i < MS_CHUNK; i += 256) atomicAdd(&hist[key[e0 + i] >> 8], 1);
    __syncthreads();
    int hv = (t < NBINS) ? hist[t] : 0;
    sm[t] = hv;
    __syncthreads();
    for (int off = 1; off < 256; off <<= 1) {
        int a = (t >= off) ? sm[t - off] : 0;
        __syncthreads();
        sm[t] += a;
        __syncthreads();
    }
    if (t < NBINS) {
        int ex = sm[t] - hv;
        int g = atomicAdd(side ? &cur_s[t] : &cur_d[t], hv);  // one atomic per bin per block
        delta[t] = g - ex;
        lcur[t] = ex;
    }
    __syncthreads();
    if (side == 0) {
        for (int i = t; i < MS_CHUNK; i += 256) {
            int kf = key[e0 + i];
            int v = src[e0 + i];
            int b = kf >> 8;
            int pos = atomicAdd(&lcur[b], 1);
            stage[pos] = ((kf & 255) << 16) | v;   // src < 2^16
            binof[pos] = (unsigned char)b;
        }
        __syncthreads();
        for (int i = t; i < MS_CHUNK; i += 256)
            binned_d[i + delta[binof[i]]] = stage[i];  // ~160B contiguous segments
    } else {
        for (int i = t; i < MS_CHUNK; i += 256) {
            int kf = key[e0 + i];
            int b = kf >> 8;
            int pos = atomicAdd(&lcur[b], 1);
            stage[pos] = kf & 255;
            binof[pos] = (unsigned char)b;
        }
        __syncthreads();
        for (int i = t; i < MS_CHUNK; i += 256)
            binned_s[i + delta[binof[i]]] = (unsigned char)stage[i];
    }
}

// per-bin counting sort -> final CSR + offsets + deg^{-1/2}; src bins -> dout only
__global__ __launch_bounds__(256) void k_bins(const int* __restrict__ binned_d,
                                              const unsigned char* __restrict__ binned_s,
                                              const int* __restrict__ bo_d, const int* __restrict__ bo_s,
                                              int* __restrict__ offsets, float* __restrict__ din,
                                              float* __restrict__ dout, int* __restrict__ csr) {
    __shared__ int hist[256];
    __shared__ int sm[256];
    __shared__ int cur[256];
    __shared__ int stage[BIN_CAP];
    int t = threadIdx.x;
    hist[t] = 0;
    __syncthreads();
    if (blockIdx.x < NBINS) {
        int bin = blockIdx.x;
        int beg = bo_d[bin], end = bo_d[bin + 1];
        int n = end - beg;
        for (int i = t; i < n; i += 256) atomicAdd(&hist[binned_d[beg + i] >> 16], 1);
        __syncthreads();
        int hv = hist[t];
        sm[t] = hv;
        __syncthreads();
        for (int off = 1; off < 256; off <<= 1) {
            int a = (t >= off) ? sm[t - off] : 0;
            __syncthreads();
            sm[t] += a;
            __syncthreads();
        }
        int ex = sm[t] - hv;
        int node = bin * 256 + t;
        if (node < N_NODES) {
            offsets[node] = beg + ex;
            din[node] = hv ? rsqrtf((float)hv) : 0.f;
        }
        cur[t] = ex;
        __syncthreads();
        for (int i = t; i < n; i += 256) {
            int p = binned_d[beg + i];
            int pos = atomicAdd(&cur[p >> 16], 1);
            if (pos < BIN_CAP) stage[pos] = p & 0xFFFF;
        }
        __syncthreads();
        int m = n < BIN_CAP ? n : BIN_CAP;
        for (int i = t; i < m; i += 256) csr[beg + i] = stage[i];
    } else {
        int bin = blockIdx.x - NBINS;
        int beg = bo_s[bin], end = bo_s[bin + 1];
        for (int i = t; i < end - beg; i += 256) atomicAdd(&hist[binned_s[beg + i]], 1);
        __syncthreads();
        int node = bin * 256 + t;
        if (node < N_NODES) {
            int hv2 = hist[t];
            dout[node] = hv2 ? rsqrtf((float)hv2) : 0.f;
        }
    }
}

// ---------------- GEMM1 (MFMA bf16): h slices = (x @ W1) * dout[row] ----------
// Slice-major output: hbs[slice][node][c], slice = col>>4 == nt, c = col&15.
// Each 1.6 MB slice is gathered by exactly one XCD in k_agg1.

__global__ __launch_bounds__(256) void k_gemm1(const float* __restrict__ x,
                                               const short* __restrict__ w1f,
                                               const float* __restrict__ dout,
                                               _Float16* __restrict__ hbs) {
    int t = threadIdx.x;
    int wv = t >> 6, lane = t & 63;
    int q = lane >> 4, lr = lane & 15;
    int m0 = blockIdx.x * 64 + wv * 16;
    int row = m0 + lr;
    int rowc = min(row, N_NODES - 1);      // clamp: tail rows read row 49999, stores guarded
    v4f acc[8];
#pragma unroll
    for (int n = 0; n < 8; n++) acc[n] = (v4f){0.f, 0.f, 0.f, 0.f};

    const float* xr = &x[(size_t)rowc * IN_F];
#pragma unroll
    for (int kt = 0; kt < 8; kt++) {
        const float4* ap = (const float4*)&xr[kt * 32 + q * 8];
        float4 a0 = ap[0], a1 = ap[1];
        short8 af;
        af[0] = (short)f2bf(a0.x); af[1] = (short)f2bf(a0.y);
        af[2] = (short)f2bf(a0.z); af[3] = (short)f2bf(a0.w);
        af[4] = (short)f2bf(a1.x); af[5] = (short)f2bf(a1.y);
        af[6] = (short)f2bf(a1.z); af[7] = (short)f2bf(a1.w);
#pragma unroll
        for (int nt = 0; nt < 8; nt++) {
            short8 bf = *(const short8*)&w1f[(size_t)((kt * 8 + nt) * 64 + lane) * 8];
            acc[nt] = __builtin_amdgcn_mfma_f32_16x16x32_bf16(af, bf, acc[nt], 0, 0, 0);
        }
    }
    int rbase = m0 + q * 4;
    float4 dv = *(const float4*)&dout[rbase];
#pragma unroll
    for (int i = 0; i < 4; i++) {
        int orow = rbase + i;
        if (orow < N_NODES) {
            float s = (i == 0) ? dv.x : (i == 1) ? dv.y : (i == 2) ? dv.z : dv.w;
#pragma unroll
            for (int nt = 0; nt < 8; nt++)
                hbs[((size_t)nt * NP + orow) * 16 + lr] = (_Float16)(acc[nt][i] * s);
        }
    }
}

// ---------------- Aggregation layer 1: XCD-sliced f16 gather ------------------
// slice = blockIdx & 7 (round-robin blockIdx->XCD): each XCD gathers only its
// 1.6 MB slice (L2-resident). 2 lanes x 16 B per edge-slice, 32 edge slots.

__global__ __launch_bounds__(256) void k_agg1(const int* __restrict__ csr,
                                              const int* __restrict__ offsets,
                                              const _Float16* __restrict__ hbs,
                                              const float* __restrict__ din,
                                              const float* __restrict__ b1,
                                              float* __restrict__ out1) {
    int slice = blockIdx.x & 7;
    int wid = (int)((blockIdx.x >> 3) * 4 + (threadIdx.x >> 6));
    int lane = threadIdx.x & 63;
    if (wid >= N_NODES) return;
    int beg = offsets[wid];
    int end = (wid + 1 < N_NODES) ? offsets[wid + 1] : N_EDGES;
    int grp = lane >> 1;      // 32 edge slots
    int l = lane & 1;
    int colb = l * 8;         // 8 f16 cols of the 16-col slice per lane
    const _Float16* hp = hbs + (size_t)slice * NP * 16;
    h2v a0 = (h2v)0, a1 = (h2v)0, a2 = (h2v)0, a3 = (h2v)0;
    for (int base = beg; base < end; base += 64) {
        int idx = base + lane;
        int sv = (idx < end) ? csr[idx] : 0;
        int cnt = min(64, end - base);
        int e0 = grp, e1 = grp + 32;
        int s0 = __shfl(sv, min(e0, cnt - 1));
        int s1 = __shfl(sv, min(e1, cnt - 1));
        // 2 independent clamped loads in flight (L2-resident slice)
        uint4 v0 = *(const uint4*)&hp[(size_t)s0 * 16 + colb];
        uint4 v1 = *(const uint4*)&hp[(size_t)s1 * 16 + colb];
        if (e0 < cnt) { a0 += u2h(v0.x); a1 += u2h(v0.y); a2 += u2h(v0.z); a3 += u2h(v0.w); }
        if (e1 < cnt) { a0 += u2h(v1.x); a1 += u2h(v1.y); a2 += u2h(v1.z); a3 += u2h(v1.w); }
    }
    float c[8];
    c[0] = (float)a0[0]; c[1] = (float)a0[1];
    c[2] = (float)a1[0]; c[3] = (float)a1[1];
    c[4] = (float)a2[0]; c[5] = (float)a2[1];
    c[6] = (float)a3[0]; c[7] = (float)a3[1];
#pragma unroll
    for (int i = 0; i < 8; i++) {
        c[i] += __shfl_xor(c[i], 2);
        c[i] += __shfl_xor(c[i], 4);
        c[i] += __shfl_xor(c[i], 8);
        c[i] += __shfl_xor(c[i], 16);
        c[i] += __shfl_xor(c[i], 32);
    }
    if (grp == 0) {   // lanes 0 and 1
        float sc = din[wid];
        int cb = slice * 16 + colb;
        float4 bb0 = *(const float4*)&b1[cb];
        float4 bb1 = *(const float4*)&b1[cb + 4];
        float4 o0 = make_float4(c[0] * sc + bb0.x, c[1] * sc + bb0.y,
                                c[2] * sc + bb0.z, c[3] * sc + bb0.w);
        float4 o1 = make_float4(c[4] * sc + bb1.x, c[5] * sc + bb1.y,
                                c[6] * sc + bb1.z, c[7] * sc + bb1.w);
        *(float4*)&out1[(size_t)wid * HID + cb] = o0;
        *(float4*)&out1[(size_t)wid * HID + cb + 4] = o1;
    }
}

// ---------------- GEMM2: h2_f16 = (out1 @ W2) * deg_out_isqrt[row] ------------

__global__ __launch_bounds__(256) void k_gemm2(const float* __restrict__ out1,
                                               const float* __restrict__ W2,
                                               const float* __restrict__ dout,
                                               _Float16* __restrict__ h2b) {
    __shared__ float ws[HID * NCLS];  // 20 KB
    int t = threadIdx.x;
    for (int i = t; i < HID * NCLS; i += 256) ws[i] = W2[i];
    __syncthreads();
    int n = blockIdx.x * 256 + t;
    if (n >= N_NODES) return;
    float acc[NCLS];
#pragma unroll
    for (int c = 0; c < NCLS; c++) acc[c] = 0.f;
    const float* xr = &out1[(size_t)n * HID];
    for (int k = 0; k < HID; k += 4) {
        float4 xv = *(const float4*)&xr[k];
#pragma unroll
        for (int c4 = 0; c4 < NCLS / 4; c4++) {
            float4 w0 = *(const float4*)&ws[(k + 0) * NCLS + c4 * 4];
            float4 w1 = *(const float4*)&ws[(k + 1) * NCLS + c4 * 4];
            float4 w2 = *(const float4*)&ws[(k + 2) * NCLS + c4 * 4];
            float4 w3 = *(const float4*)&ws[(k + 3) * NCLS + c4 * 4];
            acc[c4 * 4 + 0] += xv.x * w0.x + xv.y * w1.x + xv.z * w2.x + xv.w * w3.x;
            acc[c4 * 4 + 1] += xv.x * w0.y + xv.y * w1.y + xv.z * w2.y + xv.w * w3.y;
            acc[c4 * 4 + 2] += xv.x * w0.z + xv.y * w1.z + xv.z * w2.z + xv.w * w3.z;
            acc[c4 * 4 + 3] += xv.x * w0.w + xv.y * w1.w + xv.z * w2.w + xv.w * w3.w;
        }
    }
    float s = dout[n];
#pragma unroll
    for (int c4 = 0; c4 < NCLS / 4; c4++) {
        h2v p0, p1;
        p0[0] = (_Float16)(acc[c4 * 4 + 0] * s);
        p0[1] = (_Float16)(acc[c4 * 4 + 1] * s);
        p1[0] = (_Float16)(acc[c4 * 4 + 2] * s);
        p1[1] = (_Float16)(acc[c4 * 4 + 3] * s);
        uint2 o = make_uint2(h2u(p0), h2u(p1));
        *(uint2*)&h2b[(size_t)n * HS2 + c4 * 4] = o;
    }
}

// ---------------- Aggregation layer 2 + bias + log_softmax --------------------
// 8 edge slots x 8 lanes (5 active, 16 B each), 4 loads in flight.

__global__ __launch_bounds__(256) void k_agg2(const int* __restrict__ csr,
                                              const int* __restrict__ offsets,
                                              const _Float16* __restrict__ h2b,
                                              const float* __restrict__ din,
                                              const float* __restrict__ b2,
                                              float* __restrict__ out) {
    int wid = (int)((blockIdx.x * 256 + threadIdx.x) >> 6);
    int lane = threadIdx.x & 63;
    if (wid >= N_NODES) return;
    int beg = offsets[wid];
    int end = (wid + 1 < N_NODES) ? offsets[wid + 1] : N_EDGES;
    int grp = lane >> 3;      // 8 edge slots
    int l = lane & 7;
    bool act = l < 5;         // 5 lanes x 8 cols = 40
    int colb = min(l, 4) * 8;
    h2v a0 = (h2v)0, a1 = (h2v)0, a2 = (h2v)0, a3 = (h2v)0;
    for (int base = beg; base < end; base += 64) {
        int idx = base + lane;
        int sv = (idx < end) ? csr[idx] : 0;
        int cnt = min(64, end - base);
        for (int j = 0; j < cnt; j += 32) {
            int e0 = j + grp, e1 = e0 + 8, e2 = e0 + 16, e3 = e0 + 24;
            int s0 = __shfl(sv, min(e0, cnt - 1));
            int s1 = __shfl(sv, min(e1, cnt - 1));
            int s2 = __shfl(sv, min(e2, cnt - 1));
            int s3 = __shfl(sv, min(e3, cnt - 1));
            if (act) {
                uint4 v0 = *(const uint4*)&h2b[(size_t)s0 * HS2 + colb];
                uint4 v1 = *(const uint4*)&h2b[(size_t)s1 * HS2 + colb];
                uint4 v2 = *(const uint4*)&h2b[(size_t)s2 * HS2 + colb];
                uint4 v3 = *(const uint4*)&h2b[(size_t)s3 * HS2 + colb];
                if (e0 < cnt) { a0 += u2h(v0.x); a1 += u2h(v0.y); a2 += u2h(v0.z); a3 += u2h(v0.w); }
                if (e1 < cnt) { a0 += u2h(v1.x); a1 += u2h(v1.y); a2 += u2h(v1.z); a3 += u2h(v1.w); }
                if (e2 < cnt) { a0 += u2h(v2.x); a1 += u2h(v2.y); a2 += u2h(v2.z); a3 += u2h(v2.w); }
                if (e3 < cnt) { a0 += u2h(v3.x); a1 += u2h(v3.y); a2 += u2h(v3.z); a3 += u2h(v3.w); }
            }
        }
    }
    float c[8];
    c[0] = (float)a0[0]; c[1] = (float)a0[1];
    c[2] = (float)a1[0]; c[3] = (float)a1[1];
    c[4] = (float)a2[0]; c[5] = (float)a2[1];
    c[6] = (float)a3[0]; c[7] = (float)a3[1];
#pragma unroll
    for (int i = 0; i < 8; i++) {
        c[i] += __shfl_xor(c[i], 8);
        c[i] += __shfl_xor(c[i], 16);
        c[i] += __shfl_xor(c[i], 32);
    }
    float sc = din[wid];
    float y[8];
    float lm = -INFINITY;
    if (act) {
        float4 bb0 = *(const float4*)&b2[colb];
        float4 bb1 = *(const float4*)&b2[colb + 4];
        y[0] = c[0] * sc + bb0.x; y[1] = c[1] * sc + bb0.y;
        y[2] = c[2] * sc + bb0.z; y[3] = c[3] * sc + bb0.w;
        y[4] = c[4] * sc + bb1.x; y[5] = c[5] * sc + bb1.y;
        y[6] = c[6] * sc + bb1.z; y[7] = c[7] * sc + bb1.w;
#pragma unroll
        for (int i = 0; i < 8; i++) lm = fmaxf(lm, y[i]);
    }
#pragma unroll
    for (int off = 1; off < 8; off <<= 1) lm = fmaxf(lm, __shfl_xor(lm, off));
    float ls = 0.f;
    if (act) {
#pragma unroll
        for (int i = 0; i < 8; i++) ls += expf(y[i] - lm);
    }
#pragma unroll
    for (int off = 1; off < 8; off <<= 1) ls += __shfl_xor(ls, off);
    if (grp == 0 && act) {
        float lg = logf(ls);
        float4 o0 = make_float4(y[0] - lm - lg, y[1] - lm - lg, y[2] - lm - lg, y[3] - lm - lg);
        float4 o1 = make_float4(y[4] - lm - lg, y[5] - lm - lg, y[6] - lm - lg, y[7] - lm - lg);
        *(float4*)&out[(size_t)wid * NCLS + colb] = o0;
        *(float4*)&out[(size_t)wid * NCLS + colb + 4] = o1;
    }
}

// ---------------- launch ----------------

extern "C" void kernel_launch(void* const* d_in, const int* in_sizes, int n_in,
                              void* d_out, int out_size, void* d_ws, size_t ws_size,
                              hipStream_t stream) {
    const float* x  = (const float*)d_in[0];
    const int* src  = (const int*)d_in[1];
    const int* dst  = (const int*)d_in[2];
    const float* W1 = (const float*)d_in[3];
    const float* b1 = (const float*)d_in[4];
    const float* W2 = (const float*)d_in[5];
    const float* b2 = (const float*)d_in[6];
    float* out = (float*)d_out;

    int* wsi   = (int*)d_ws;
    float* wsf = (float*)d_ws;
    // workspace layout (4B units):
    int* hist_g   = wsi;                      // [0,392)
    int* bo_d     = wsi + 512;                // 197
    int* bo_s     = wsi + 768;                // 197
    int* cur_d    = wsi + 1024;               // 196
    int* cur_s    = wsi + 1280;               // 196
    int* offsets  = wsi + 1536;               // NP
    float* din    = wsf + 1536 + (size_t)NP;      // NP
    float* dout   = wsf + 1536 + 2 * (size_t)NP;  // NP
    int* binned_d = wsi + 1536 + 3 * (size_t)NP;  // N_EDGES ints (csr aliases)
    unsigned char* binned_s = (unsigned char*)(binned_d + N_EDGES);      // N_EDGES bytes
    _Float16* hbs = (_Float16*)(binned_s + N_EDGES);                     // 8*NP*16 f16 (12.8 MB)
    float* out1   = (float*)(hbs + 8 * (size_t)NP * 16);                 // N*HID fp32 (25.6 MB)
    short* w1f    = (short*)(out1 + (size_t)N_NODES * HID);              // 32768 bf16 (64 KB)
    int* csr      = binned_d;          // in-place per-bin sort (safe: see k_bins)
    _Float16* h2b = hbs;               // hbs dead after agg1; N*HS2 f16 fits (4.0 MB)

    const int NB = (N_NODES + 255) / 256;   // 196
    const int NG = (N_NODES + 3) / 4;       // 12500 node groups

    k_w1cvt<<<17, 256, 0, stream>>>(W1, w1f, hist_g);
    k_bincount<<<BC_BLOCKS, 256, 0, stream>>>(src, dst, hist_g);
    k_binscan<<<1, 256, 0, stream>>>(hist_g, bo_d, bo_s, cur_d, cur_s);
    k_msscatter<<<2 * MS_BLOCKS, 256, 0, stream>>>(src, dst, cur_d, cur_s, binned_d, binned_s);
    k_bins<<<2 * NBINS, 256, 0, stream>>>(binned_d, binned_s, bo_d, bo_s, offsets, din, dout, csr);
    k_gemm1<<<(N_NODES + 63) / 64, 256, 0, stream>>>(x, w1f, dout, hbs);
    k_agg1<<<NG * 8, 256, 0, stream>>>(csr, offsets, hbs, din, b1, out1);
    k_gemm2<<<NB, 256, 0, stream>>>(out1, W2, dout, h2b);
    k_agg2<<<(N_NODES + 3) / 4, 256, 0, stream>>>(csr, offsets, h2b, din, b2, out);
}

// Round 11
// 276.528 us; speedup vs baseline: 1.4728x; 1.4728x over previous
//
#include <hip/hip_runtime.h>
#include <math.h>

#define N_NODES 50000
#define N_EDGES 1600000
#define IN_F 256
#define HID 128
#define NCLS 40
#define HS2 40        // f16 row stride for h2 (80 B exact; table = 4.0 MB)
#define NP 50048      // padded node count (ws layout)
#define NBINS 196     // ceil(50000/256) coarse bins of 256 nodes
#define MS_BLOCKS 200
#define MS_CHUNK 8000 // MS_BLOCKS * MS_CHUNK == N_EDGES
#define BC_BLOCKS 400
#define BC_CHUNK 4000 // BC_BLOCKS * BC_CHUNK == N_EDGES
#define BIN_CAP 12288 // max edges per 256-node bin (mean 8192, sigma ~90)

typedef __attribute__((ext_vector_type(8))) short short8;     // 8 bf16 (4 VGPRs)
typedef __attribute__((ext_vector_type(4))) float v4f;        // MFMA acc
typedef __attribute__((ext_vector_type(2))) _Float16 h2v;     // packed f16 pair

__device__ __forceinline__ unsigned short f2bf(float f) {
    union { float f; unsigned int i; } v;
    v.f = f;
    unsigned int r = v.i + 0x7FFF + ((v.i >> 16) & 1);  // RNE
    return (unsigned short)(r >> 16);
}
__device__ __forceinline__ h2v u2h(unsigned int u) {
    union { unsigned int i; h2v h; } v; v.i = u; return v.h;
}
__device__ __forceinline__ unsigned int h2u(h2v h) {
    union { h2v h; unsigned int i; } v; v.h = h; return v.i;
}

// ---------------- W1 preconvert + hist zero (fused) ---------------------------
// blocks 0..15: w1f fragment-order convert; block 16: zero hist_g (strided).

__global__ __launch_bounds__(256) void k_w1cvt(const float* __restrict__ W1,
                                               short* __restrict__ w1f,
                                               int* __restrict__ hist_g) {
    if (blockIdx.x == 16) {
        for (int i = threadIdx.x; i < 2 * NBINS; i += 256) hist_g[i] = 0;
        return;
    }
    int g = blockIdx.x * 256 + threadIdx.x;   // slot id: 8 kt * 8 nt * 64 lanes = 4096
    int lane = g & 63, nt = (g >> 6) & 7, kt = g >> 9;
    int q = lane >> 4, n = lane & 15;
    short8 v;
#pragma unroll
    for (int j = 0; j < 8; j++) {
        int k = kt * 32 + q * 8 + j;
        v[j] = (short)f2bf(W1[(size_t)k * HID + nt * 16 + n]);
    }
    *(short8*)&w1f[(size_t)g * 8] = v;
}

// ---------------- binned CSR construction (no random atomics/stores) ----------

__global__ __launch_bounds__(256) void k_bincount(const int* __restrict__ src,
                                                  const int* __restrict__ dst,
                                                  int* __restrict__ hist_g) {
    __shared__ int h[2 * NBINS];
    int t = threadIdx.x;
    for (int i = t; i < 2 * NBINS; i += 256) h[i] = 0;
    __syncthreads();
    int e0 = blockIdx.x * BC_CHUNK;
    for (int i = t * 4; i < BC_CHUNK; i += 1024) {   // int4-vectorized edge reads
        int4 d4 = *(const int4*)&dst[e0 + i];
        int4 s4 = *(const int4*)&src[e0 + i];
        atomicAdd(&h[d4.x >> 8], 1);
        atomicAdd(&h[d4.y >> 8], 1);
        atomicAdd(&h[d4.z >> 8], 1);
        atomicAdd(&h[d4.w >> 8], 1);
        atomicAdd(&h[NBINS + (s4.x >> 8)], 1);
        atomicAdd(&h[NBINS + (s4.y >> 8)], 1);
        atomicAdd(&h[NBINS + (s4.z >> 8)], 1);
        atomicAdd(&h[NBINS + (s4.w >> 8)], 1);
    }
    __syncthreads();
    for (int i = t; i < 2 * NBINS; i += 256)
        if (h[i]) atomicAdd(&hist_g[i], h[i]);
}

__global__ __launch_bounds__(256) void k_binscan(const int* __restrict__ hist_g,
                                                 int* __restrict__ bo_d, int* __restrict__ bo_s,
                                                 int* __restrict__ cur_d, int* __restrict__ cur_s) {
    __shared__ int sm[256];
    int t = threadIdx.x;
    for (int side = 0; side < 2; side++) {
        int v = (t < NBINS) ? hist_g[side * NBINS + t] : 0;
        sm[t] = v;
        __syncthreads();
        for (int off = 1; off < 256; off <<= 1) {
            int a = (t >= off) ? sm[t - off] : 0;
            __syncthreads();
            sm[t] += a;
            __syncthreads();
        }
        int ex = sm[t] - v;
        int* bo = side ? bo_s : bo_d;
        int* cu = side ? cur_s : cur_d;
        if (t < NBINS) { bo[t] = ex; cu[t] = ex; }
        if (t == 0) bo[NBINS] = N_EDGES;
        __syncthreads();
    }
}

// multisplit: blocks [0,200) key=dst (payload src, packed int), blocks [200,400) key=src (1B payload)
__global__ __launch_bounds__(256) void k_msscatter(const int* __restrict__ src,
                                                   const int* __restrict__ dst,
                                                   int* __restrict__ cur_d, int* __restrict__ cur_s,
                                                   int* __restrict__ binned_d,
                                                   unsigned char* __restrict__ binned_s) {
    __shared__ int hist[NBINS];
    __shared__ int delta[NBINS];
    __shared__ int lcur[NBINS];
    __shared__ int sm[256];
    __shared__ int stage[MS_CHUNK];
    __shared__ unsigned char binof[MS_CHUNK];
    int t = threadIdx.x;
    int side = blockIdx.x / MS_BLOCKS;
    int e0 = (blockIdx.x % MS_BLOCKS) * MS_CHUNK;
    const int* key = side ? src : dst;
    for (int i = t; i < NBINS; i += 256) hist[i] = 0;
    __syncthreads();
    for (int i = t; i < MS_CHUNK; i += 256) atomicAdd(&hist[key[e0 + i] >> 8], 1);
    __syncthreads();
    int hv = (t < NBINS) ? hist[t] : 0;
    sm[t] = hv;
    __syncthreads();
    for (int off = 1; off < 256; off <<= 1) {
        int a = (t >= off) ? sm[t - off] : 0;
        __syncthreads();
        sm[t] += a;
        __syncthreads();
    }
    if (t < NBINS) {
        int ex = sm[t] - hv;
        int g = atomicAdd(side ? &cur_s[t] : &cur_d[t], hv);  // one atomic per bin per block
        delta[t] = g - ex;
        lcur[t] = ex;
    }
    __syncthreads();
    if (side == 0) {
        for (int i = t; i < MS_CHUNK; i += 256) {
            int kf = key[e0 + i];
            int v = src[e0 + i];
            int b = kf >> 8;
            int pos = atomicAdd(&lcur[b], 1);
            stage[pos] = ((kf & 255) << 16) | v;   // src < 2^16
            binof[pos] = (unsigned char)b;
        }
        __syncthreads();
        for (int i = t; i < MS_CHUNK; i += 256)
            binned_d[i + delta[binof[i]]] = stage[i];  // ~160B contiguous segments
    } else {
        for (int i = t; i < MS_CHUNK; i += 256) {
            int kf = key[e0 + i];
            int b = kf >> 8;
            int pos = atomicAdd(&lcur[b], 1);
            stage[pos] = kf & 255;
            binof[pos] = (unsigned char)b;
        }
        __syncthreads();
        for (int i = t; i < MS_CHUNK; i += 256)
            binned_s[i + delta[binof[i]]] = (unsigned char)stage[i];
    }
}

// per-bin counting sort -> final CSR + offsets + deg^{-1/2}; src bins -> dout only
__global__ __launch_bounds__(256) void k_bins(const int* __restrict__ binned_d,
                                              const unsigned char* __restrict__ binned_s,
                                              const int* __restrict__ bo_d, const int* __restrict__ bo_s,
                                              int* __restrict__ offsets, float* __restrict__ din,
                                              float* __restrict__ dout, int* __restrict__ csr) {
    __shared__ int hist[256];
    __shared__ int sm[256];
    __shared__ int cur[256];
    __shared__ int stage[BIN_CAP];
    int t = threadIdx.x;
    hist[t] = 0;
    __syncthreads();
    if (blockIdx.x < NBINS) {
        int bin = blockIdx.x;
        int beg = bo_d[bin], end = bo_d[bin + 1];
        int n = end - beg;
        for (int i = t; i < n; i += 256) atomicAdd(&hist[binned_d[beg + i] >> 16], 1);
        __syncthreads();
        int hv = hist[t];
        sm[t] = hv;
        __syncthreads();
        for (int off = 1; off < 256; off <<= 1) {
            int a = (t >= off) ? sm[t - off] : 0;
            __syncthreads();
            sm[t] += a;
            __syncthreads();
        }
        int ex = sm[t] - hv;
        int node = bin * 256 + t;
        if (node < N_NODES) {
            offsets[node] = beg + ex;
            din[node] = hv ? rsqrtf((float)hv) : 0.f;
        }
        cur[t] = ex;
        __syncthreads();
        for (int i = t; i < n; i += 256) {
            int p = binned_d[beg + i];
            int pos = atomicAdd(&cur[p >> 16], 1);
            if (pos < BIN_CAP) stage[pos] = p & 0xFFFF;
        }
        __syncthreads();
        int m = n < BIN_CAP ? n : BIN_CAP;
        for (int i = t; i < m; i += 256) csr[beg + i] = stage[i];
    } else {
        int bin = blockIdx.x - NBINS;
        int beg = bo_s[bin], end = bo_s[bin + 1];
        for (int i = t; i < end - beg; i += 256) atomicAdd(&hist[binned_s[beg + i]], 1);
        __syncthreads();
        int node = bin * 256 + t;
        if (node < N_NODES) {
            int hv2 = hist[t];
            dout[node] = hv2 ? rsqrtf((float)hv2) : 0.f;
        }
    }
}

// ---------------- GEMM1 (MFMA bf16): h_f16 = (x @ W1) * dout[row] -------------

__global__ __launch_bounds__(256) void k_gemm1(const float* __restrict__ x,
                                               const short* __restrict__ w1f,
                                               const float* __restrict__ dout,
                                               _Float16* __restrict__ hb) {
    int t = threadIdx.x;
    int wv = t >> 6, lane = t & 63;
    int q = lane >> 4, lr = lane & 15;
    int m0 = blockIdx.x * 64 + wv * 16;
    int row = m0 + lr;
    int rowc = min(row, N_NODES - 1);      // clamp: tail rows read row 49999, stores guarded
    v4f acc[8];
#pragma unroll
    for (int n = 0; n < 8; n++) acc[n] = (v4f){0.f, 0.f, 0.f, 0.f};

    const float* xr = &x[(size_t)rowc * IN_F];
#pragma unroll
    for (int kt = 0; kt < 8; kt++) {
        const float4* ap = (const float4*)&xr[kt * 32 + q * 8];
        float4 a0 = ap[0], a1 = ap[1];
        short8 af;
        af[0] = (short)f2bf(a0.x); af[1] = (short)f2bf(a0.y);
        af[2] = (short)f2bf(a0.z); af[3] = (short)f2bf(a0.w);
        af[4] = (short)f2bf(a1.x); af[5] = (short)f2bf(a1.y);
        af[6] = (short)f2bf(a1.z); af[7] = (short)f2bf(a1.w);
#pragma unroll
        for (int nt = 0; nt < 8; nt++) {
            short8 bf = *(const short8*)&w1f[(size_t)((kt * 8 + nt) * 64 + lane) * 8];
            acc[nt] = __builtin_amdgcn_mfma_f32_16x16x32_bf16(af, bf, acc[nt], 0, 0, 0);
        }
    }
    int rbase = m0 + q * 4;
    float4 dv = *(const float4*)&dout[rbase];
#pragma unroll
    for (int i = 0; i < 4; i++) {
        int orow = rbase + i;
        if (orow < N_NODES) {
            float s = (i == 0) ? dv.x : (i == 1) ? dv.y : (i == 2) ? dv.z : dv.w;
#pragma unroll
            for (int nt = 0; nt < 8; nt++)
                hb[(size_t)orow * HID + nt * 16 + lr] = (_Float16)(acc[nt][i] * s);
        }
    }
}

// ---------------- Aggregation layer 1: f16 gather, ILP-4 (round-9 proven) -----
// 16 lanes x 16 B per edge-row (256 B), 4 edge slots, 4 clamped loads in flight.

__global__ __launch_bounds__(256) void k_agg1(const int* __restrict__ csr,
                                              const int* __restrict__ offsets,
                                              const _Float16* __restrict__ hb,
                                              const float* __restrict__ din,
                                              const float* __restrict__ b1,
                                              float* __restrict__ out1) {
    int wid = (int)((blockIdx.x * 256 + threadIdx.x) >> 6);
    int lane = threadIdx.x & 63;
    if (wid >= N_NODES) return;
    int beg = offsets[wid];
    int end = (wid + 1 < N_NODES) ? offsets[wid + 1] : N_EDGES;
    int grp = lane >> 4;      // 4 edge slots
    int l = lane & 15;
    int colb = l * 8;         // 8 f16 columns per lane
    h2v a0 = (h2v)0, a1 = (h2v)0, a2 = (h2v)0, a3 = (h2v)0;
    for (int base = beg; base < end; base += 64) {
        int idx = base + lane;
        int sv = (idx < end) ? csr[idx] : 0;
        int cnt = min(64, end - base);
        for (int j = 0; j < cnt; j += 16) {
            int e0 = j + grp, e1 = e0 + 4, e2 = e0 + 8, e3 = e0 + 12;
            int s0 = __shfl(sv, min(e0, cnt - 1));
            int s1 = __shfl(sv, min(e1, cnt - 1));
            int s2 = __shfl(sv, min(e2, cnt - 1));
            int s3 = __shfl(sv, min(e3, cnt - 1));
            // 4 independent clamped loads in flight (dups hit cache)
            uint4 v0 = *(const uint4*)&hb[(size_t)s0 * HID + colb];
            uint4 v1 = *(const uint4*)&hb[(size_t)s1 * HID + colb];
            uint4 v2 = *(const uint4*)&hb[(size_t)s2 * HID + colb];
            uint4 v3 = *(const uint4*)&hb[(size_t)s3 * HID + colb];
            if (e0 < cnt) { a0 += u2h(v0.x); a1 += u2h(v0.y); a2 += u2h(v0.z); a3 += u2h(v0.w); }
            if (e1 < cnt) { a0 += u2h(v1.x); a1 += u2h(v1.y); a2 += u2h(v1.z); a3 += u2h(v1.w); }
            if (e2 < cnt) { a0 += u2h(v2.x); a1 += u2h(v2.y); a2 += u2h(v2.z); a3 += u2h(v2.w); }
            if (e3 < cnt) { a0 += u2h(v3.x); a1 += u2h(v3.y); a2 += u2h(v3.z); a3 += u2h(v3.w); }
        }
    }
    float c[8];
    c[0] = (float)a0[0]; c[1] = (float)a0[1];
    c[2] = (float)a1[0]; c[3] = (float)a1[1];
    c[4] = (float)a2[0]; c[5] = (float)a2[1];
    c[6] = (float)a3[0]; c[7] = (float)a3[1];
#pragma unroll
    for (int i = 0; i < 8; i++) {
        c[i] += __shfl_xor(c[i], 16);
        c[i] += __shfl_xor(c[i], 32);
    }
    if (grp == 0) {
        float sc = din[wid];
        float4 bb0 = *(const float4*)&b1[colb];
        float4 bb1 = *(const float4*)&b1[colb + 4];
        float4 o0 = make_float4(c[0] * sc + bb0.x, c[1] * sc + bb0.y,
                                c[2] * sc + bb0.z, c[3] * sc + bb0.w);
        float4 o1 = make_float4(c[4] * sc + bb1.x, c[5] * sc + bb1.y,
                                c[6] * sc + bb1.z, c[7] * sc + bb1.w);
        *(float4*)&out1[(size_t)wid * HID + colb] = o0;
        *(float4*)&out1[(size_t)wid * HID + colb + 4] = o1;
    }
}

// ---------------- GEMM2: h2_f16 = (out1 @ W2) * deg_out_isqrt[row] ------------

__global__ __launch_bounds__(256) void k_gemm2(const float* __restrict__ out1,
                                               const float* __restrict__ W2,
                                               const float* __restrict__ dout,
                                               _Float16* __restrict__ h2b) {
    __shared__ float ws[HID * NCLS];  // 20 KB
    int t = threadIdx.x;
    for (int i = t; i < HID * NCLS; i += 256) ws[i] = W2[i];
    __syncthreads();
    int n = blockIdx.x * 256 + t;
    if (n >= N_NODES) return;
    float acc[NCLS];
#pragma unroll
    for (int c = 0; c < NCLS; c++) acc[c] = 0.f;
    const float* xr = &out1[(size_t)n * HID];
    for (int k = 0; k < HID; k += 4) {
        float4 xv = *(const float4*)&xr[k];
#pragma unroll
        for (int c4 = 0; c4 < NCLS / 4; c4++) {
            float4 w0 = *(const float4*)&ws[(k + 0) * NCLS + c4 * 4];
            float4 w1 = *(const float4*)&ws[(k + 1) * NCLS + c4 * 4];
            float4 w2 = *(const float4*)&ws[(k + 2) * NCLS + c4 * 4];
            float4 w3 = *(const float4*)&ws[(k + 3) * NCLS + c4 * 4];
            acc[c4 * 4 + 0] += xv.x * w0.x + xv.y * w1.x + xv.z * w2.x + xv.w * w3.x;
            acc[c4 * 4 + 1] += xv.x * w0.y + xv.y * w1.y + xv.z * w2.y + xv.w * w3.y;
            acc[c4 * 4 + 2] += xv.x * w0.z + xv.y * w1.z + xv.z * w2.z + xv.w * w3.z;
            acc[c4 * 4 + 3] += xv.x * w0.w + xv.y * w1.w + xv.z * w2.w + xv.w * w3.w;
        }
    }
    float s = dout[n];
#pragma unroll
    for (int c4 = 0; c4 < NCLS / 4; c4++) {
        h2v p0, p1;
        p0[0] = (_Float16)(acc[c4 * 4 + 0] * s);
        p0[1] = (_Float16)(acc[c4 * 4 + 1] * s);
        p1[0] = (_Float16)(acc[c4 * 4 + 2] * s);
        p1[1] = (_Float16)(acc[c4 * 4 + 3] * s);
        uint2 o = make_uint2(h2u(p0), h2u(p1));
        *(uint2*)&h2b[(size_t)n * HS2 + c4 * 4] = o;
    }
}

// ---------------- Aggregation layer 2 + bias + log_softmax --------------------
// 8 edge slots x 8 lanes (5 active, 16 B each), 4 loads in flight.

__global__ __launch_bounds__(256) void k_agg2(const int* __restrict__ csr,
                                              const int* __restrict__ offsets,
                                              const _Float16* __restrict__ h2b,
                                              const float* __restrict__ din,
                                              const float* __restrict__ b2,
                                              float* __restrict__ out) {
    int wid = (int)((blockIdx.x * 256 + threadIdx.x) >> 6);
    int lane = threadIdx.x & 63;
    if (wid >= N_NODES) return;
    int beg = offsets[wid];
    int end = (wid + 1 < N_NODES) ? offsets[wid + 1] : N_EDGES;
    int grp = lane >> 3;      // 8 edge slots
    int l = lane & 7;
    bool act = l < 5;         // 5 lanes x 8 cols = 40
    int colb = min(l, 4) * 8;
    h2v a0 = (h2v)0, a1 = (h2v)0, a2 = (h2v)0, a3 = (h2v)0;
    for (int base = beg; base < end; base += 64) {
        int idx = base + lane;
        int sv = (idx < end) ? csr[idx] : 0;
        int cnt = min(64, end - base);
        for (int j = 0; j < cnt; j += 32) {
            int e0 = j + grp, e1 = e0 + 8, e2 = e0 + 16, e3 = e0 + 24;
            int s0 = __shfl(sv, min(e0, cnt - 1));
            int s1 = __shfl(sv, min(e1, cnt - 1));
            int s2 = __shfl(sv, min(e2, cnt - 1));
            int s3 = __shfl(sv, min(e3, cnt - 1));
            if (act) {
                uint4 v0 = *(const uint4*)&h2b[(size_t)s0 * HS2 + colb];
                uint4 v1 = *(const uint4*)&h2b[(size_t)s1 * HS2 + colb];
                uint4 v2 = *(const uint4*)&h2b[(size_t)s2 * HS2 + colb];
                uint4 v3 = *(const uint4*)&h2b[(size_t)s3 * HS2 + colb];
                if (e0 < cnt) { a0 += u2h(v0.x); a1 += u2h(v0.y); a2 += u2h(v0.z); a3 += u2h(v0.w); }
                if (e1 < cnt) { a0 += u2h(v1.x); a1 += u2h(v1.y); a2 += u2h(v1.z); a3 += u2h(v1.w); }
                if (e2 < cnt) { a0 += u2h(v2.x); a1 += u2h(v2.y); a2 += u2h(v2.z); a3 += u2h(v2.w); }
                if (e3 < cnt) { a0 += u2h(v3.x); a1 += u2h(v3.y); a2 += u2h(v3.z); a3 += u2h(v3.w); }
            }
        }
    }
    float c[8];
    c[0] = (float)a0[0]; c[1] = (float)a0[1];
    c[2] = (float)a1[0]; c[3] = (float)a1[1];
    c[4] = (float)a2[0]; c[5] = (float)a2[1];
    c[6] = (float)a3[0]; c[7] = (float)a3[1];
#pragma unroll
    for (int i = 0; i < 8; i++) {
        c[i] += __shfl_xor(c[i], 8);
        c[i] += __shfl_xor(c[i], 16);
        c[i] += __shfl_xor(c[i], 32);
    }
    float sc = din[wid];
    float y[8];
    float lm = -INFINITY;
    if (act) {
        float4 bb0 = *(const float4*)&b2[colb];
        float4 bb1 = *(const float4*)&b2[colb + 4];
        y[0] = c[0] * sc + bb0.x; y[1] = c[1] * sc + bb0.y;
        y[2] = c[2] * sc + bb0.z; y[3] = c[3] * sc + bb0.w;
        y[4] = c[4] * sc + bb1.x; y[5] = c[5] * sc + bb1.y;
        y[6] = c[6] * sc + bb1.z; y[7] = c[7] * sc + bb1.w;
#pragma unroll
        for (int i = 0; i < 8; i++) lm = fmaxf(lm, y[i]);
    }
#pragma unroll
    for (int off = 1; off < 8; off <<= 1) lm = fmaxf(lm, __shfl_xor(lm, off));
    float ls = 0.f;
    if (act) {
#pragma unroll
        for (int i = 0; i < 8; i++) ls += expf(y[i] - lm);
    }
#pragma unroll
    for (int off = 1; off < 8; off <<= 1) ls += __shfl_xor(ls, off);
    if (grp == 0 && act) {
        float lg = logf(ls);
        float4 o0 = make_float4(y[0] - lm - lg, y[1] - lm - lg, y[2] - lm - lg, y[3] - lm - lg);
        float4 o1 = make_float4(y[4] - lm - lg, y[5] - lm - lg, y[6] - lm - lg, y[7] - lm - lg);
        *(float4*)&out[(size_t)wid * NCLS + colb] = o0;
        *(float4*)&out[(size_t)wid * NCLS + colb + 4] = o1;
    }
}

// ---------------- launch ----------------

extern "C" void kernel_launch(void* const* d_in, const int* in_sizes, int n_in,
                              void* d_out, int out_size, void* d_ws, size_t ws_size,
                              hipStream_t stream) {
    const float* x  = (const float*)d_in[0];
    const int* src  = (const int*)d_in[1];
    const int* dst  = (const int*)d_in[2];
    const float* W1 = (const float*)d_in[3];
    const float* b1 = (const float*)d_in[4];
    const float* W2 = (const float*)d_in[5];
    const float* b2 = (const float*)d_in[6];
    float* out = (float*)d_out;

    int* wsi   = (int*)d_ws;
    float* wsf = (float*)d_ws;
    // workspace layout (4B units):
    int* hist_g   = wsi;                      // [0,392)
    int* bo_d     = wsi + 512;                // 197
    int* bo_s     = wsi + 768;                // 197
    int* cur_d    = wsi + 1024;               // 196
    int* cur_s    = wsi + 1280;               // 196
    int* offsets  = wsi + 1536;               // NP
    float* din    = wsf + 1536 + (size_t)NP;      // NP
    float* dout   = wsf + 1536 + 2 * (size_t)NP;  // NP
    int* binned_d = wsi + 1536 + 3 * (size_t)NP;  // N_EDGES ints (csr aliases)
    unsigned char* binned_s = (unsigned char*)(binned_d + N_EDGES);      // N_EDGES bytes
    _Float16* hb  = (_Float16*)(binned_s + N_EDGES);                     // N*HID f16 (12.8 MB)
    float* out1   = (float*)(hb + (size_t)N_NODES * HID);                // N*HID fp32 (25.6 MB)
    short* w1f    = (short*)(out1 + (size_t)N_NODES * HID);              // 32768 bf16 (64 KB)
    int* csr      = binned_d;          // in-place per-bin sort (safe: see k_bins)
    _Float16* h2b = hb;                // hb dead after agg1; N*HS2 f16 fits (4.0 MB)

    const int NB = (N_NODES + 255) / 256;   // 196

    k_w1cvt<<<17, 256, 0, stream>>>(W1, w1f, hist_g);
    k_bincount<<<BC_BLOCKS, 256, 0, stream>>>(src, dst, hist_g);
    k_binscan<<<1, 256, 0, stream>>>(hist_g, bo_d, bo_s, cur_d, cur_s);
    k_msscatter<<<2 * MS_BLOCKS, 256, 0, stream>>>(src, dst, cur_d, cur_s, binned_d, binned_s);
    k_bins<<<2 * NBINS, 256, 0, stream>>>(binned_d, binned_s, bo_d, bo_s, offsets, din, dout, csr);
    k_gemm1<<<(N_NODES + 63) / 64, 256, 0, stream>>>(x, w1f, dout, hb);
    k_agg1<<<(N_NODES + 3) / 4, 256, 0, stream>>>(csr, offsets, hb, din, b1, out1);
    k_gemm2<<<NB, 256, 0, stream>>>(out1, W2, dout, h2b);
    k_agg2<<<(N_NODES + 3) / 4, 256, 0, stream>>>(csr, offsets, h2b, din, b2, out);
}

// Round 12
// 275.927 us; speedup vs baseline: 1.4760x; 1.0022x over previous
//
#include <hip/hip_runtime.h>
#include <math.h>

#define N_NODES 50000
#define N_EDGES 1600000
#define IN_F 256
#define HID 128
#define NCLS 40
#define HS2 40        // f16 row stride for h2 (80 B exact; table = 4.0 MB)
#define NP 50048      // padded node count (ws layout)
#define NBINS 196     // ceil(50000/256) coarse bins of 256 nodes
#define MS_BLOCKS 200
#define MS_CHUNK 8000 // MS_BLOCKS * MS_CHUNK == N_EDGES
#define BC_BLOCKS 400
#define BC_CHUNK 4000 // BC_BLOCKS * BC_CHUNK == N_EDGES
#define BIN_CAP 12288 // max edges per 256-node bin (mean 8192, sigma ~90)

typedef __attribute__((ext_vector_type(8))) short short8;     // 8 bf16 (4 VGPRs)
typedef __attribute__((ext_vector_type(4))) float v4f;        // MFMA acc
typedef __attribute__((ext_vector_type(2))) _Float16 h2v;     // packed f16 pair

__device__ __forceinline__ unsigned short f2bf(float f) {
    union { float f; unsigned int i; } v;
    v.f = f;
    unsigned int r = v.i + 0x7FFF + ((v.i >> 16) & 1);  // RNE
    return (unsigned short)(r >> 16);
}
__device__ __forceinline__ h2v u2h(unsigned int u) {
    union { unsigned int i; h2v h; } v; v.i = u; return v.h;
}
__device__ __forceinline__ unsigned int h2u(h2v h) {
    union { h2v h; unsigned int i; } v; v.h = h; return v.i;
}

// ---------------- W1 preconvert + hist zero (fused) ---------------------------

__global__ __launch_bounds__(256) void k_w1cvt(const float* __restrict__ W1,
                                               short* __restrict__ w1f,
                                               int* __restrict__ hist_g) {
    if (blockIdx.x == 16) {
        for (int i = threadIdx.x; i < 2 * NBINS; i += 256) hist_g[i] = 0;
        return;
    }
    int g = blockIdx.x * 256 + threadIdx.x;   // slot id: 8 kt * 8 nt * 64 lanes = 4096
    int lane = g & 63, nt = (g >> 6) & 7, kt = g >> 9;
    int q = lane >> 4, n = lane & 15;
    short8 v;
#pragma unroll
    for (int j = 0; j < 8; j++) {
        int k = kt * 32 + q * 8 + j;
        v[j] = (short)f2bf(W1[(size_t)k * HID + nt * 16 + n]);
    }
    *(short8*)&w1f[(size_t)g * 8] = v;
}

// ---------------- binned CSR construction (no random atomics/stores) ----------

__global__ __launch_bounds__(256) void k_bincount(const int* __restrict__ src,
                                                  const int* __restrict__ dst,
                                                  int* __restrict__ hist_g) {
    __shared__ int h[2 * NBINS];
    int t = threadIdx.x;
    for (int i = t; i < 2 * NBINS; i += 256) h[i] = 0;
    __syncthreads();
    int e0 = blockIdx.x * BC_CHUNK;
    for (int i = t * 4; i < BC_CHUNK; i += 1024) {   // int4-vectorized edge reads
        int4 d4 = *(const int4*)&dst[e0 + i];
        int4 s4 = *(const int4*)&src[e0 + i];
        atomicAdd(&h[d4.x >> 8], 1);
        atomicAdd(&h[d4.y >> 8], 1);
        atomicAdd(&h[d4.z >> 8], 1);
        atomicAdd(&h[d4.w >> 8], 1);
        atomicAdd(&h[NBINS + (s4.x >> 8)], 1);
        atomicAdd(&h[NBINS + (s4.y >> 8)], 1);
        atomicAdd(&h[NBINS + (s4.z >> 8)], 1);
        atomicAdd(&h[NBINS + (s4.w >> 8)], 1);
    }
    __syncthreads();
    for (int i = t; i < 2 * NBINS; i += 256)
        if (h[i]) atomicAdd(&hist_g[i], h[i]);
}

__global__ __launch_bounds__(256) void k_binscan(const int* __restrict__ hist_g,
                                                 int* __restrict__ bo_d, int* __restrict__ bo_s,
                                                 int* __restrict__ cur_d, int* __restrict__ cur_s) {
    __shared__ int sm[256];
    int t = threadIdx.x;
    for (int side = 0; side < 2; side++) {
        int v = (t < NBINS) ? hist_g[side * NBINS + t] : 0;
        sm[t] = v;
        __syncthreads();
        for (int off = 1; off < 256; off <<= 1) {
            int a = (t >= off) ? sm[t - off] : 0;
            __syncthreads();
            sm[t] += a;
            __syncthreads();
        }
        int ex = sm[t] - v;
        int* bo = side ? bo_s : bo_d;
        int* cu = side ? cur_s : cur_d;
        if (t < NBINS) { bo[t] = ex; cu[t] = ex; }
        if (t == 0) bo[NBINS] = N_EDGES;
        __syncthreads();
    }
}

// multisplit: blocks [0,200) key=dst (payload src, packed int), blocks [200,400) key=src (1B payload)
__global__ __launch_bounds__(256) void k_msscatter(const int* __restrict__ src,
                                                   const int* __restrict__ dst,
                                                   int* __restrict__ cur_d, int* __restrict__ cur_s,
                                                   int* __restrict__ binned_d,
                                                   unsigned char* __restrict__ binned_s) {
    __shared__ int hist[NBINS];
    __shared__ int delta[NBINS];
    __shared__ int lcur[NBINS];
    __shared__ int sm[256];
    __shared__ int stage[MS_CHUNK];
    __shared__ unsigned char binof[MS_CHUNK];
    int t = threadIdx.x;
    int side = blockIdx.x / MS_BLOCKS;
    int e0 = (blockIdx.x % MS_BLOCKS) * MS_CHUNK;
    const int* key = side ? src : dst;
    for (int i = t; i < NBINS; i += 256) hist[i] = 0;
    __syncthreads();
    for (int i = t; i < MS_CHUNK; i += 256) atomicAdd(&hist[key[e0 + i] >> 8], 1);
    __syncthreads();
    int hv = (t < NBINS) ? hist[t] : 0;
    sm[t] = hv;
    __syncthreads();
    for (int off = 1; off < 256; off <<= 1) {
        int a = (t >= off) ? sm[t - off] : 0;
        __syncthreads();
        sm[t] += a;
        __syncthreads();
    }
    if (t < NBINS) {
        int ex = sm[t] - hv;
        int g = atomicAdd(side ? &cur_s[t] : &cur_d[t], hv);  // one atomic per bin per block
        delta[t] = g - ex;
        lcur[t] = ex;
    }
    __syncthreads();
    if (side == 0) {
        for (int i = t; i < MS_CHUNK; i += 256) {
            int kf = key[e0 + i];
            int v = src[e0 + i];
            int b = kf >> 8;
            int pos = atomicAdd(&lcur[b], 1);
            stage[pos] = ((kf & 255) << 16) | v;   // src < 2^16
            binof[pos] = (unsigned char)b;
        }
        __syncthreads();
        for (int i = t; i < MS_CHUNK; i += 256)
            binned_d[i + delta[binof[i]]] = stage[i];  // ~160B contiguous segments
    } else {
        for (int i = t; i < MS_CHUNK; i += 256) {
            int kf = key[e0 + i];
            int b = kf >> 8;
            int pos = atomicAdd(&lcur[b], 1);
            stage[pos] = kf & 255;
            binof[pos] = (unsigned char)b;
        }
        __syncthreads();
        for (int i = t; i < MS_CHUNK; i += 256)
            binned_s[i + delta[binof[i]]] = (unsigned char)stage[i];
    }
}

// per-bin counting sort -> final CSR + offsets + deg^{-1/2}; src bins -> dout only
__global__ __launch_bounds__(256) void k_bins(const int* __restrict__ binned_d,
                                              const unsigned char* __restrict__ binned_s,
                                              const int* __restrict__ bo_d, const int* __restrict__ bo_s,
                                              int* __restrict__ offsets, float* __restrict__ din,
                                              float* __restrict__ dout, int* __restrict__ csr) {
    __shared__ int hist[256];
    __shared__ int sm[256];
    __shared__ int cur[256];
    __shared__ int stage[BIN_CAP];
    int t = threadIdx.x;
    hist[t] = 0;
    __syncthreads();
    if (blockIdx.x < NBINS) {
        int bin = blockIdx.x;
        int beg = bo_d[bin], end = bo_d[bin + 1];
        int n = end - beg;
        for (int i = t; i < n; i += 256) atomicAdd(&hist[binned_d[beg + i] >> 16], 1);
        __syncthreads();
        int hv = hist[t];
        sm[t] = hv;
        __syncthreads();
        for (int off = 1; off < 256; off <<= 1) {
            int a = (t >= off) ? sm[t - off] : 0;
            __syncthreads();
            sm[t] += a;
            __syncthreads();
        }
        int ex = sm[t] - hv;
        int node = bin * 256 + t;
        if (node < N_NODES) {
            offsets[node] = beg + ex;
            din[node] = hv ? rsqrtf((float)hv) : 0.f;
        }
        cur[t] = ex;
        __syncthreads();
        for (int i = t; i < n; i += 256) {
            int p = binned_d[beg + i];
            int pos = atomicAdd(&cur[p >> 16], 1);
            if (pos < BIN_CAP) stage[pos] = p & 0xFFFF;
        }
        __syncthreads();
        int m = n < BIN_CAP ? n : BIN_CAP;
        for (int i = t; i < m; i += 256) csr[beg + i] = stage[i];
    } else {
        int bin = blockIdx.x - NBINS;
        int beg = bo_s[bin], end = bo_s[bin + 1];
        for (int i = t; i < end - beg; i += 256) atomicAdd(&hist[binned_s[beg + i]], 1);
        __syncthreads();
        int node = bin * 256 + t;
        if (node < N_NODES) {
            int hv2 = hist[t];
            dout[node] = hv2 ? rsqrtf((float)hv2) : 0.f;
        }
    }
}

// ---------------- GEMM1 (MFMA bf16): h_f16 = (x @ W1) * dout[row] -------------

__global__ __launch_bounds__(256) void k_gemm1(const float* __restrict__ x,
                                               const short* __restrict__ w1f,
                                               const float* __restrict__ dout,
                                               _Float16* __restrict__ hb) {
    int t = threadIdx.x;
    int wv = t >> 6, lane = t & 63;
    int q = lane >> 4, lr = lane & 15;
    int m0 = blockIdx.x * 64 + wv * 16;
    int row = m0 + lr;
    int rowc = min(row, N_NODES - 1);      // clamp: tail rows read row 49999, stores guarded
    v4f acc[8];
#pragma unroll
    for (int n = 0; n < 8; n++) acc[n] = (v4f){0.f, 0.f, 0.f, 0.f};

    const float* xr = &x[(size_t)rowc * IN_F];
#pragma unroll
    for (int kt = 0; kt < 8; kt++) {
        const float4* ap = (const float4*)&xr[kt * 32 + q * 8];
        float4 a0 = ap[0], a1 = ap[1];
        short8 af;
        af[0] = (short)f2bf(a0.x); af[1] = (short)f2bf(a0.y);
        af[2] = (short)f2bf(a0.z); af[3] = (short)f2bf(a0.w);
        af[4] = (short)f2bf(a1.x); af[5] = (short)f2bf(a1.y);
        af[6] = (short)f2bf(a1.z); af[7] = (short)f2bf(a1.w);
#pragma unroll
        for (int nt = 0; nt < 8; nt++) {
            short8 bf = *(const short8*)&w1f[(size_t)((kt * 8 + nt) * 64 + lane) * 8];
            acc[nt] = __builtin_amdgcn_mfma_f32_16x16x32_bf16(af, bf, acc[nt], 0, 0, 0);
        }
    }
    int rbase = m0 + q * 4;
    float4 dv = *(const float4*)&dout[rbase];
#pragma unroll
    for (int i = 0; i < 4; i++) {
        int orow = rbase + i;
        if (orow < N_NODES) {
            float s = (i == 0) ? dv.x : (i == 1) ? dv.y : (i == 2) ? dv.z : dv.w;
#pragma unroll
            for (int nt = 0; nt < 8; nt++)
                hb[(size_t)orow * HID + nt * 16 + lr] = (_Float16)(acc[nt][i] * s);
        }
    }
}

// ---------------- Aggregation layer 1: f16 gather, ILP-8, f16 out1 ------------
// 16 lanes x 16 B per edge-row (256 B), 4 edge slots, 8 clamped loads in flight.

__global__ __launch_bounds__(256) void k_agg1(const int* __restrict__ csr,
                                              const int* __restrict__ offsets,
                                              const _Float16* __restrict__ hb,
                                              const float* __restrict__ din,
                                              const float* __restrict__ b1,
                                              _Float16* __restrict__ out1) {
    int wid = (int)((blockIdx.x * 256 + threadIdx.x) >> 6);
    int lane = threadIdx.x & 63;
    if (wid >= N_NODES) return;
    int beg = offsets[wid];
    int end = (wid + 1 < N_NODES) ? offsets[wid + 1] : N_EDGES;
    int grp = lane >> 4;      // 4 edge slots
    int l = lane & 15;
    int colb = l * 8;         // 8 f16 columns per lane
    h2v a0 = (h2v)0, a1 = (h2v)0, a2 = (h2v)0, a3 = (h2v)0;
    for (int base = beg; base < end; base += 64) {
        int idx = base + lane;
        int sv = (idx < end) ? csr[idx] : 0;
        int cnt = min(64, end - base);
        for (int j = 0; j < cnt; j += 32) {
            int e0 = j + grp, e1 = e0 + 4, e2 = e0 + 8, e3 = e0 + 12;
            int e4 = e0 + 16, e5 = e0 + 20, e6 = e0 + 24, e7 = e0 + 28;
            int s0 = __shfl(sv, min(e0, cnt - 1));
            int s1 = __shfl(sv, min(e1, cnt - 1));
            int s2 = __shfl(sv, min(e2, cnt - 1));
            int s3 = __shfl(sv, min(e3, cnt - 1));
            int s4 = __shfl(sv, min(e4, cnt - 1));
            int s5 = __shfl(sv, min(e5, cnt - 1));
            int s6 = __shfl(sv, min(e6, cnt - 1));
            int s7 = __shfl(sv, min(e7, cnt - 1));
            // 8 independent clamped loads in flight (dups hit cache)
            uint4 v0 = *(const uint4*)&hb[(size_t)s0 * HID + colb];
            uint4 v1 = *(const uint4*)&hb[(size_t)s1 * HID + colb];
            uint4 v2 = *(const uint4*)&hb[(size_t)s2 * HID + colb];
            uint4 v3 = *(const uint4*)&hb[(size_t)s3 * HID + colb];
            uint4 v4 = *(const uint4*)&hb[(size_t)s4 * HID + colb];
            uint4 v5 = *(const uint4*)&hb[(size_t)s5 * HID + colb];
            uint4 v6 = *(const uint4*)&hb[(size_t)s6 * HID + colb];
            uint4 v7 = *(const uint4*)&hb[(size_t)s7 * HID + colb];
            if (e0 < cnt) { a0 += u2h(v0.x); a1 += u2h(v0.y); a2 += u2h(v0.z); a3 += u2h(v0.w); }
            if (e1 < cnt) { a0 += u2h(v1.x); a1 += u2h(v1.y); a2 += u2h(v1.z); a3 += u2h(v1.w); }
            if (e2 < cnt) { a0 += u2h(v2.x); a1 += u2h(v2.y); a2 += u2h(v2.z); a3 += u2h(v2.w); }
            if (e3 < cnt) { a0 += u2h(v3.x); a1 += u2h(v3.y); a2 += u2h(v3.z); a3 += u2h(v3.w); }
            if (e4 < cnt) { a0 += u2h(v4.x); a1 += u2h(v4.y); a2 += u2h(v4.z); a3 += u2h(v4.w); }
            if (e5 < cnt) { a0 += u2h(v5.x); a1 += u2h(v5.y); a2 += u2h(v5.z); a3 += u2h(v5.w); }
            if (e6 < cnt) { a0 += u2h(v6.x); a1 += u2h(v6.y); a2 += u2h(v6.z); a3 += u2h(v6.w); }
            if (e7 < cnt) { a0 += u2h(v7.x); a1 += u2h(v7.y); a2 += u2h(v7.z); a3 += u2h(v7.w); }
        }
    }
    float c[8];
    c[0] = (float)a0[0]; c[1] = (float)a0[1];
    c[2] = (float)a1[0]; c[3] = (float)a1[1];
    c[4] = (float)a2[0]; c[5] = (float)a2[1];
    c[6] = (float)a3[0]; c[7] = (float)a3[1];
#pragma unroll
    for (int i = 0; i < 8; i++) {
        c[i] += __shfl_xor(c[i], 16);
        c[i] += __shfl_xor(c[i], 32);
    }
    if (grp == 0) {
        float sc = din[wid];
        float4 bb0 = *(const float4*)&b1[colb];
        float4 bb1 = *(const float4*)&b1[colb + 4];
        h2v p0, p1, p2, p3;
        p0[0] = (_Float16)(c[0] * sc + bb0.x); p0[1] = (_Float16)(c[1] * sc + bb0.y);
        p1[0] = (_Float16)(c[2] * sc + bb0.z); p1[1] = (_Float16)(c[3] * sc + bb0.w);
        p2[0] = (_Float16)(c[4] * sc + bb1.x); p2[1] = (_Float16)(c[5] * sc + bb1.y);
        p3[0] = (_Float16)(c[6] * sc + bb1.z); p3[1] = (_Float16)(c[7] * sc + bb1.w);
        uint4 o;
        o.x = h2u(p0); o.y = h2u(p1); o.z = h2u(p2); o.w = h2u(p3);
        *(uint4*)&out1[(size_t)wid * HID + colb] = o;
    }
}

// ---------------- GEMM2: h2_f16 = (out1_f16 @ W2) * deg_out_isqrt[row] --------

__global__ __launch_bounds__(256) void k_gemm2(const _Float16* __restrict__ out1,
                                               const float* __restrict__ W2,
                                               const float* __restrict__ dout,
                                               _Float16* __restrict__ h2b) {
    __shared__ float ws[HID * NCLS];  // 20 KB
    int t = threadIdx.x;
    for (int i = t; i < HID * NCLS; i += 256) ws[i] = W2[i];
    __syncthreads();
    int n = blockIdx.x * 256 + t;
    if (n >= N_NODES) return;
    float acc[NCLS];
#pragma unroll
    for (int c = 0; c < NCLS; c++) acc[c] = 0.f;
    const _Float16* xr = &out1[(size_t)n * HID];
    for (int k = 0; k < HID; k += 4) {
        uint2 xraw = *(const uint2*)&xr[k];
        h2v x01 = u2h(xraw.x), x23 = u2h(xraw.y);
        float xv0 = (float)x01[0], xv1 = (float)x01[1];
        float xv2 = (float)x23[0], xv3 = (float)x23[1];
#pragma unroll
        for (int c4 = 0; c4 < NCLS / 4; c4++) {
            float4 w0 = *(const float4*)&ws[(k + 0) * NCLS + c4 * 4];
            float4 w1 = *(const float4*)&ws[(k + 1) * NCLS + c4 * 4];
            float4 w2 = *(const float4*)&ws[(k + 2) * NCLS + c4 * 4];
            float4 w3 = *(const float4*)&ws[(k + 3) * NCLS + c4 * 4];
            acc[c4 * 4 + 0] += xv0 * w0.x + xv1 * w1.x + xv2 * w2.x + xv3 * w3.x;
            acc[c4 * 4 + 1] += xv0 * w0.y + xv1 * w1.y + xv2 * w2.y + xv3 * w3.y;
            acc[c4 * 4 + 2] += xv0 * w0.z + xv1 * w1.z + xv2 * w2.z + xv3 * w3.z;
            acc[c4 * 4 + 3] += xv0 * w0.w + xv1 * w1.w + xv2 * w2.w + xv3 * w3.w;
        }
    }
    float s = dout[n];
#pragma unroll
    for (int c4 = 0; c4 < NCLS / 4; c4++) {
        h2v p0, p1;
        p0[0] = (_Float16)(acc[c4 * 4 + 0] * s);
        p0[1] = (_Float16)(acc[c4 * 4 + 1] * s);
        p1[0] = (_Float16)(acc[c4 * 4 + 2] * s);
        p1[1] = (_Float16)(acc[c4 * 4 + 3] * s);
        uint2 o = make_uint2(h2u(p0), h2u(p1));
        *(uint2*)&h2b[(size_t)n * HS2 + c4 * 4] = o;
    }
}

// ---------------- Aggregation layer 2 + bias + log_softmax --------------------
// 8 edge slots x 8 lanes (5 active, 16 B each), 8 loads in flight (full window).

__global__ __launch_bounds__(256) void k_agg2(const int* __restrict__ csr,
                                              const int* __restrict__ offsets,
                                              const _Float16* __restrict__ h2b,
                                              const float* __restrict__ din,
                                              const float* __restrict__ b2,
                                              float* __restrict__ out) {
    int wid = (int)((blockIdx.x * 256 + threadIdx.x) >> 6);
    int lane = threadIdx.x & 63;
    if (wid >= N_NODES) return;
    int beg = offsets[wid];
    int end = (wid + 1 < N_NODES) ? offsets[wid + 1] : N_EDGES;
    int grp = lane >> 3;      // 8 edge slots
    int l = lane & 7;
    bool act = l < 5;         // 5 lanes x 8 cols = 40
    int colb = min(l, 4) * 8;
    h2v a0 = (h2v)0, a1 = (h2v)0, a2 = (h2v)0, a3 = (h2v)0;
    for (int base = beg; base < end; base += 64) {
        int idx = base + lane;
        int sv = (idx < end) ? csr[idx] : 0;
        int cnt = min(64, end - base);
        int e0 = grp, e1 = grp + 8, e2 = grp + 16, e3 = grp + 24;
        int e4 = grp + 32, e5 = grp + 40, e6 = grp + 48, e7 = grp + 56;
        int s0 = __shfl(sv, min(e0, cnt - 1));
        int s1 = __shfl(sv, min(e1, cnt - 1));
        int s2 = __shfl(sv, min(e2, cnt - 1));
        int s3 = __shfl(sv, min(e3, cnt - 1));
        int s4 = __shfl(sv, min(e4, cnt - 1));
        int s5 = __shfl(sv, min(e5, cnt - 1));
        int s6 = __shfl(sv, min(e6, cnt - 1));
        int s7 = __shfl(sv, min(e7, cnt - 1));
        if (act) {
            uint4 v0 = *(const uint4*)&h2b[(size_t)s0 * HS2 + colb];
            uint4 v1 = *(const uint4*)&h2b[(size_t)s1 * HS2 + colb];
            uint4 v2 = *(const uint4*)&h2b[(size_t)s2 * HS2 + colb];
            uint4 v3 = *(const uint4*)&h2b[(size_t)s3 * HS2 + colb];
            uint4 v4 = *(const uint4*)&h2b[(size_t)s4 * HS2 + colb];
            uint4 v5 = *(const uint4*)&h2b[(size_t)s5 * HS2 + colb];
            uint4 v6 = *(const uint4*)&h2b[(size_t)s6 * HS2 + colb];
            uint4 v7 = *(const uint4*)&h2b[(size_t)s7 * HS2 + colb];
            if (e0 < cnt) { a0 += u2h(v0.x); a1 += u2h(v0.y); a2 += u2h(v0.z); a3 += u2h(v0.w); }
            if (e1 < cnt) { a0 += u2h(v1.x); a1 += u2h(v1.y); a2 += u2h(v1.z); a3 += u2h(v1.w); }
            if (e2 < cnt) { a0 += u2h(v2.x); a1 += u2h(v2.y); a2 += u2h(v2.z); a3 += u2h(v2.w); }
            if (e3 < cnt) { a0 += u2h(v3.x); a1 += u2h(v3.y); a2 += u2h(v3.z); a3 += u2h(v3.w); }
            if (e4 < cnt) { a0 += u2h(v4.x); a1 += u2h(v4.y); a2 += u2h(v4.z); a3 += u2h(v4.w); }
            if (e5 < cnt) { a0 += u2h(v5.x); a1 += u2h(v5.y); a2 += u2h(v5.z); a3 += u2h(v5.w); }
            if (e6 < cnt) { a0 += u2h(v6.x); a1 += u2h(v6.y); a2 += u2h(v6.z); a3 += u2h(v6.w); }
            if (e7 < cnt) { a0 += u2h(v7.x); a1 += u2h(v7.y); a2 += u2h(v7.z); a3 += u2h(v7.w); }
        }
    }
    float c[8];
    c[0] = (float)a0[0]; c[1] = (float)a0[1];
    c[2] = (float)a1[0]; c[3] = (float)a1[1];
    c[4] = (float)a2[0]; c[5] = (float)a2[1];
    c[6] = (float)a3[0]; c[7] = (float)a3[1];
#pragma unroll
    for (int i = 0; i < 8; i++) {
        c[i] += __shfl_xor(c[i], 8);
        c[i] += __shfl_xor(c[i], 16);
        c[i] += __shfl_xor(c[i], 32);
    }
    float sc = din[wid];
    float y[8];
    float lm = -INFINITY;
    if (act) {
        float4 bb0 = *(const float4*)&b2[colb];
        float4 bb1 = *(const float4*)&b2[colb + 4];
        y[0] = c[0] * sc + bb0.x; y[1] = c[1] * sc + bb0.y;
        y[2] = c[2] * sc + bb0.z; y[3] = c[3] * sc + bb0.w;
        y[4] = c[4] * sc + bb1.x; y[5] = c[5] * sc + bb1.y;
        y[6] = c[6] * sc + bb1.z; y[7] = c[7] * sc + bb1.w;
#pragma unroll
        for (int i = 0; i < 8; i++) lm = fmaxf(lm, y[i]);
    }
#pragma unroll
    for (int off = 1; off < 8; off <<= 1) lm = fmaxf(lm, __shfl_xor(lm, off));
    float ls = 0.f;
    if (act) {
#pragma unroll
        for (int i = 0; i < 8; i++) ls += expf(y[i] - lm);
    }
#pragma unroll
    for (int off = 1; off < 8; off <<= 1) ls += __shfl_xor(ls, off);
    if (grp == 0 && act) {
        float lg = logf(ls);
        float4 o0 = make_float4(y[0] - lm - lg, y[1] - lm - lg, y[2] - lm - lg, y[3] - lm - lg);
        float4 o1 = make_float4(y[4] - lm - lg, y[5] - lm - lg, y[6] - lm - lg, y[7] - lm - lg);
        *(float4*)&out[(size_t)wid * NCLS + colb] = o0;
        *(float4*)&out[(size_t)wid * NCLS + colb + 4] = o1;
    }
}

// ---------------- launch ----------------

extern "C" void kernel_launch(void* const* d_in, const int* in_sizes, int n_in,
                              void* d_out, int out_size, void* d_ws, size_t ws_size,
                              hipStream_t stream) {
    const float* x  = (const float*)d_in[0];
    const int* src  = (const int*)d_in[1];
    const int* dst  = (const int*)d_in[2];
    const float* W1 = (const float*)d_in[3];
    const float* b1 = (const float*)d_in[4];
    const float* W2 = (const float*)d_in[5];
    const float* b2 = (const float*)d_in[6];
    float* out = (float*)d_out;

    int* wsi   = (int*)d_ws;
    float* wsf = (float*)d_ws;
    // workspace layout (4B units):
    int* hist_g   = wsi;                      // [0,392)
    int* bo_d     = wsi + 512;                // 197
    int* bo_s     = wsi + 768;                // 197
    int* cur_d    = wsi + 1024;               // 196
    int* cur_s    = wsi + 1280;               // 196
    int* offsets  = wsi + 1536;               // NP
    float* din    = wsf + 1536 + (size_t)NP;      // NP
    float* dout   = wsf + 1536 + 2 * (size_t)NP;  // NP
    int* binned_d = wsi + 1536 + 3 * (size_t)NP;  // N_EDGES ints (csr aliases)
    unsigned char* binned_s = (unsigned char*)(binned_d + N_EDGES);      // N_EDGES bytes
    _Float16* hb  = (_Float16*)(binned_s + N_EDGES);                     // N*HID f16 (12.8 MB)
    _Float16* out1 = hb + (size_t)N_NODES * HID;                         // N*HID f16 (12.8 MB)
    short* w1f    = (short*)(out1 + (size_t)N_NODES * HID);              // 32768 bf16 (64 KB)
    int* csr      = binned_d;          // in-place per-bin sort (safe: see k_bins)
    _Float16* h2b = hb;                // hb dead after agg1; N*HS2 f16 fits (4.0 MB)

    const int NB = (N_NODES + 255) / 256;   // 196

    k_w1cvt<<<17, 256, 0, stream>>>(W1, w1f, hist_g);
    k_bincount<<<BC_BLOCKS, 256, 0, stream>>>(src, dst, hist_g);
    k_binscan<<<1, 256, 0, stream>>>(hist_g, bo_d, bo_s, cur_d, cur_s);
    k_msscatter<<<2 * MS_BLOCKS, 256, 0, stream>>>(src, dst, cur_d, cur_s, binned_d, binned_s);
    k_bins<<<2 * NBINS, 256, 0, stream>>>(binned_d, binned_s, bo_d, bo_s, offsets, din, dout, csr);
    k_gemm1<<<(N_NODES + 63) / 64, 256, 0, stream>>>(x, w1f, dout, hb);
    k_agg1<<<(N_NODES + 3) / 4, 256, 0, stream>>>(csr, offsets, hb, din, b1, out1);
    k_gemm2<<<NB, 256, 0, stream>>>(out1, W2, dout, h2b);
    k_agg2<<<(N_NODES + 3) / 4, 256, 0, stream>>>(csr, offsets, h2b, din, b2, out);
}